// Round 1
// baseline (37.683 us; speedup 1.0000x reference)
//
#include <hip/hip_runtime.h>

// YOLO loss: N=16384, S=7, B=2, C=20. Record stride = B*5+C = 30 floats.
// Memory-bound: 2 x 96.3 MB streamed once, scalar out.

constexpr float LC   = 5.0f;    // LAMBDA_COORD
constexpr float LN   = 0.5f;    // LAMBDA_NOOBJ
constexpr float EPSF = 1e-6f;

__device__ __forceinline__ float iou_pair(
    float cx1, float cy1, float w1, float h1,
    float cx2, float cy2, float w2, float h2) {
  float b1x1 = cx1 - w1 * 0.5f, b1x2 = cx1 + w1 * 0.5f;
  float b1y1 = cy1 - h1 * 0.5f, b1y2 = cy1 + h1 * 0.5f;
  float b2x1 = cx2 - w2 * 0.5f, b2x2 = cx2 + w2 * 0.5f;
  float b2y1 = cy2 - h2 * 0.5f, b2y2 = cy2 + h2 * 0.5f;
  float iw = fmaxf(fminf(b1x2, b2x2) - fmaxf(b1x1, b2x1), 0.0f);
  float ih = fmaxf(fminf(b1y2, b2y2) - fmaxf(b1y1, b2y1), 0.0f);
  float inter = iw * ih;
  float uni = w1 * h1 + w2 * h2 - inter;
  return inter / (uni + EPSF);
}

__global__ __launch_bounds__(256) void yolo_cell_kernel(
    const float* __restrict__ pred, const float* __restrict__ tgt,
    float* __restrict__ partial, int ncells, float invN) {
  int cell = blockIdx.x * 256 + threadIdx.x;
  float contrib = 0.0f;
  if (cell < ncells) {
    const float* p = pred + (size_t)cell * 30;
    const float* t = tgt  + (size_t)cell * 30;
    // 120B record is 8B-aligned for every cell -> float2 loads.
    float2 p01 = *(const float2*)(p + 0);
    float2 p23 = *(const float2*)(p + 2);
    float2 p45 = *(const float2*)(p + 4);
    float2 p67 = *(const float2*)(p + 6);
    float2 p89 = *(const float2*)(p + 8);
    float2 t01 = *(const float2*)(t + 0);
    float2 t23 = *(const float2*)(t + 2);
    float2 t45 = *(const float2*)(t + 4);  // t45.x = target conf; t5..t9 unused

    float iou0 = iou_pair(p01.x, p01.y, p23.x, p23.y, t01.x, t01.y, t23.x, t23.y);
    float iou1 = iou_pair(p45.y, p67.x, p67.y, p89.x, t01.x, t01.y, t23.x, t23.y);
    float v0 = iou0 > 0.0f ? iou0 : 0.0f;   // jnp.where(iou>0, iou, 0)
    float v1 = iou1 > 0.0f ? iou1 : 0.0f;
    bool pick1 = v1 > v0;                    // argmax: first index wins ties

    float bx = pick1 ? p45.y : p01.x;
    float by = pick1 ? p67.x : p01.y;
    float bw = pick1 ? p67.y : p23.x;
    float bh = pick1 ? p89.x : p23.y;
    float bc = pick1 ? p89.y : p45.x;

    float obj = t45.x > 0.0f ? 1.0f : 0.0f;

    float dx = bx - t01.x, dy = by - t01.y;
    float xy = dx * dx + dy * dy;
    float sw = sqrtf(fmaxf(bw, EPSF)) - sqrtf(fmaxf(t23.x, EPSF));
    float sh = sqrtf(fmaxf(bh, EPSF)) - sqrtf(fmaxf(t23.y, EPSF));
    float wh = sw * sw + sh * sh;

    float dc = bc - t45.x;

    float sq0 = p45.x * p45.x, sq1 = p89.y * p89.y;
    float sq_all  = sq0 + sq1;
    float sq_best = pick1 ? sq1 : sq0;
    float noobj = obj * (sq_all - sq_best) + (1.0f - obj) * sq_all;

    float cls = 0.0f;
#pragma unroll
    for (int j = 10; j < 30; j += 2) {
      float2 pc = *(const float2*)(p + j);
      float2 tc = *(const float2*)(t + j);
      float d0 = pc.x - tc.x, d1 = pc.y - tc.y;
      cls += d0 * d0 + d1 * d1;
    }

    contrib = (LC * obj * (xy + wh) + obj * dc * dc + LN * noobj + obj * cls) * invN;
  }

  // wave64 shuffle reduce, then cross-wave via LDS
  for (int off = 32; off > 0; off >>= 1)
    contrib += __shfl_down(contrib, off);
  __shared__ float wsum[4];
  int lane = threadIdx.x & 63;
  int wid  = threadIdx.x >> 6;
  if (lane == 0) wsum[wid] = contrib;
  __syncthreads();
  if (threadIdx.x == 0)
    partial[blockIdx.x] = (wsum[0] + wsum[1]) + (wsum[2] + wsum[3]);
}

__global__ __launch_bounds__(256) void yolo_final_kernel(
    const float* __restrict__ partial, int n, float* __restrict__ out) {
  double s = 0.0;
  for (int i = threadIdx.x; i < n; i += 256) s += (double)partial[i];
  for (int off = 32; off > 0; off >>= 1) s += __shfl_down(s, off);
  __shared__ double wsum[4];
  int lane = threadIdx.x & 63;
  int wid  = threadIdx.x >> 6;
  if (lane == 0) wsum[wid] = s;
  __syncthreads();
  if (threadIdx.x == 0)
    out[0] = (float)((wsum[0] + wsum[1]) + (wsum[2] + wsum[3]));
}

extern "C" void kernel_launch(void* const* d_in, const int* in_sizes, int n_in,
                              void* d_out, int out_size, void* d_ws, size_t ws_size,
                              hipStream_t stream) {
  const float* pred = (const float*)d_in[0];
  const float* tgt  = (const float*)d_in[1];
  float* out = (float*)d_out;
  float* partial = (float*)d_ws;

  int ncells  = in_sizes[0] / 30;          // N*S*S = 802816
  int nblocks = (ncells + 255) / 256;      // 3136
  int N       = ncells / 49;               // 16384
  float invN  = 1.0f / (float)N;           // exact (power of 2)

  yolo_cell_kernel<<<nblocks, 256, 0, stream>>>(pred, tgt, partial, ncells, invN);
  yolo_final_kernel<<<1, 256, 0, stream>>>(partial, nblocks, out);
}